// Round 7
// baseline (954.615 us; speedup 1.0000x reference)
//
#include <hip/hip_runtime.h>
#include <hip/hip_bf16.h>

#define HIDDEN   2880
#define INTER    2880
#define NEXP     8
#define GUP_ROWS 5760
#define NPAIR    2048

#define NKT  90              // k-tiles of 32 (both gemms)
#define BM   256
#define BN1  96              // gemm1 cols/block -> 60 nt-blocks/expert
#define BN2  64              // gemm2 cols/block -> 45 nt-blocks/expert
#define MT_GRID 8            // ceil(2048/256); extras exit

#define MAXTILES 16          // sum_e ceil(n_e/256) <= 16
#define TILE_BYTES 16384     // (tile,kt): 4 kq-planes x 256 rows x 16B
#define IMG_BYTES ((size_t)MAXTILES * NKT * TILE_BYTES)   // 23.6 MB

using bf16x8 = __attribute__((ext_vector_type(8))) short;
using f32x4  = __attribute__((ext_vector_type(4))) float;

__device__ __forceinline__ unsigned cvt2bf(float a, float b) {
  union { __hip_bfloat16 h; unsigned short s; } x, y;
  x.h = __float2bfloat16(a);
  y.h = __float2bfloat16(b);
  return (unsigned)x.s | ((unsigned)y.s << 16);
}

__device__ __forceinline__ bf16x8 cvt8(const float4& lo, const float4& hi) {
  union { bf16x8 v; unsigned u[4]; } r;
  r.u[0] = cvt2bf(lo.x, lo.y);
  r.u[1] = cvt2bf(lo.z, lo.w);
  r.u[2] = cvt2bf(hi.x, hi.y);
  r.u[3] = cvt2bf(hi.z, hi.w);
  return r.v;
}

// ---------------- routing ----------------
// meta: [0..7]=counts [8..15]=row offsets [16..23]=cursor [24..31]=tile base
__global__ void route_count(const int* __restrict__ eidx, int* __restrict__ meta) {
  __shared__ int cnt[NEXP];
  int t = threadIdx.x;
  if (t < NEXP) cnt[t] = 0;
  __syncthreads();
  for (int a = t; a < NPAIR; a += 256) atomicAdd(&cnt[eidx[a]], 1);
  __syncthreads();
  if (t == 0) {
    int off = 0, toff = 0;
    for (int e = 0; e < NEXP; ++e) {
      meta[e] = cnt[e];
      meta[8 + e] = off;
      meta[16 + e] = off;
      meta[24 + e] = toff;
      off += cnt[e];
      toff += (cnt[e] + 255) >> 8;
    }
  }
}

__global__ void route_scatter(const int* __restrict__ eidx, int* __restrict__ meta,
                              int* __restrict__ list) {
  int a = blockIdx.x * 256 + threadIdx.x;
  int e = eidx[a];
  int pos = atomicAdd(&meta[16 + e], 1);
  list[pos] = a;   // a = token*4 + slot
}

// ---------------- gather A rows -> bf16 tiled fragment image ----------------
// layout: [tile][kt][kq 0..3][row 0..255][16B]  (k index = kt*32 + kq*8 + j)
__global__ void gather_a(const float* __restrict__ t, const int* __restrict__ eidx,
                         const int* __restrict__ meta, const int* __restrict__ list,
                         char* __restrict__ atile) {
  const int i = blockIdx.x;
  const int a = list[i];
  const int e = eidx[a];
  const int r = i - meta[8 + e];
  const int tile = meta[24 + e] + (r >> 8);
  const int row = r & 255;
  const float* src = t + (size_t)(a >> 2) * HIDDEN;
  for (int ch = threadIdx.x; ch < HIDDEN / 8; ch += 256) {
    int kt = ch >> 2, kq = ch & 3;
    const float4* s = (const float4*)(src + ch * 8);
    float4 v0 = s[0], v1 = s[1];
    uint4 w;
    w.x = cvt2bf(v0.x, v0.y); w.y = cvt2bf(v0.z, v0.w);
    w.z = cvt2bf(v1.x, v1.y); w.w = cvt2bf(v1.z, v1.w);
    *(uint4*)(atile + (size_t)(tile * NKT + kt) * TILE_BYTES + kq * 4096 + row * 16) = w;
  }
}

// ---------------- GEMM1: barrier-free streaming. 8 waves (4 wm x 2 wn), wave tile 64x48 ----------------
__global__ __launch_bounds__(512, 2)
void gemm1_swiglu(const char* __restrict__ atile,
                  const float* __restrict__ gup,
                  const float* __restrict__ gub,
                  const int* __restrict__ meta,
                  char* __restrict__ utile)
{
  const int e = blockIdx.z, mt = blockIdx.y, nt = blockIdx.x;
  const int n_e = meta[e];
  const int m0 = mt * BM;
  if (m0 >= n_e) return;
  const int tile = meta[24 + e] + mt;

  const int tid = threadIdx.x, lane = tid & 63, wid = tid >> 6;
  const int wm = wid >> 1, wn = wid & 1;
  const int kq = lane >> 4, l15 = lane & 15;

  // A fragment base: per-16-lane group reads 256B contiguous per kq-plane
  const char* aBase = atile + (size_t)tile * NKT * TILE_BYTES + kq * 4096 + (wm * 64 + l15) * 16;
  // B fragment bases: per column 128B contiguous f32 per k-tile
  const char* bBase[3];
  #pragma unroll
  for (int fn = 0; fn < 3; ++fn) {
    int col = nt * BN1 + wn * 48 + fn * 16 + l15;
    bBase[fn] = (const char*)gup + (size_t)(e * GUP_ROWS + col) * (HIDDEN * 4) + kq * 32;
  }

  f32x4 acc[4][3];
  #pragma unroll
  for (int fm = 0; fm < 4; ++fm)
    #pragma unroll
    for (int fn = 0; fn < 3; ++fn)
      acc[fm][fn] = f32x4{0.f, 0.f, 0.f, 0.f};

  bf16x8 a0[4], a1[4], a2[4];
  float4 b0[3][2], b1[3][2], b2[3][2];

#define LOAD1(kt, aR, bR) { \
    const char* ap = aBase + (size_t)(kt) * TILE_BYTES; \
    _Pragma("unroll") for (int fm = 0; fm < 4; ++fm) \
      aR[fm] = *(const bf16x8*)(ap + fm * 256); \
    _Pragma("unroll") for (int fn = 0; fn < 3; ++fn) { \
      bR[fn][0] = *(const float4*)(bBase[fn] + (size_t)(kt) * 128); \
      bR[fn][1] = *(const float4*)(bBase[fn] + (size_t)(kt) * 128 + 16); } }

#define COMP1(aR, bR) { bf16x8 bb[3]; \
    _Pragma("unroll") for (int fn = 0; fn < 3; ++fn) bb[fn] = cvt8(bR[fn][0], bR[fn][1]); \
    _Pragma("unroll") for (int fm = 0; fm < 4; ++fm) \
      _Pragma("unroll") for (int fn = 0; fn < 3; ++fn) \
        acc[fm][fn] = __builtin_amdgcn_mfma_f32_16x16x32_bf16(aR[fm], bb[fn], acc[fm][fn], 0, 0, 0); }

  LOAD1(0, a0, b0);
  LOAD1(1, a1, b1);
  LOAD1(2, a2, b2);
  for (int kt = 0; kt < NKT; kt += 3) {
    COMP1(a0, b0);
    if (kt + 3 < NKT) LOAD1(kt + 3, a0, b0);
    COMP1(a1, b1);
    if (kt + 4 < NKT) LOAD1(kt + 4, a1, b1);
    COMP1(a2, b2);
    if (kt + 5 < NKT) LOAD1(kt + 5, a2, b2);
  }

  // epilogue: +bias, swiglu (even col = glu, odd = lin), write u into utile image
  #pragma unroll
  for (int fm = 0; fm < 4; ++fm) {
    #pragma unroll
    for (int fn = 0; fn < 3; ++fn) {
      const int colg = nt * BN1 + wn * 48 + fn * 16 + l15;
      const float bias = gub[e * GUP_ROWS + colg];
      #pragma unroll
      for (int j = 0; j < 4; ++j) {
        float h = acc[fm][fn][j] + bias;
        float other = __shfl_xor(h, 1, 64);
        int rowin = wm * 64 + fm * 16 + kq * 4 + j;
        if (!(lane & 1) && (m0 + rowin) < n_e) {
          float xg = fminf(h, 7.0f);
          float xl = fminf(fmaxf(other, -7.0f), 7.0f);
          float og = xg / (1.0f + __expf(-1.702f * xg));
          float uv = og * (xl + 1.0f);
          int uc = colg >> 1;   // 0..2879
          int kt2 = uc >> 5, kq2 = (uc >> 3) & 3;
          *(__hip_bfloat16*)(utile + (size_t)(tile * NKT + kt2) * TILE_BYTES +
              kq2 * 4096 + rowin * 16 + (uc & 7) * 2) = __float2bfloat16(uv);
        }
      }
    }
  }
}

// ---------------- GEMM2: barrier-free streaming. 8 waves (4 wm x 2 wn), wave tile 64x32 ----------------
__global__ __launch_bounds__(512, 2)
void gemm2_down(const char* __restrict__ utile,
                const float* __restrict__ dwn,
                const float* __restrict__ dbias,
                const int* __restrict__ meta,
                const int* __restrict__ list,
                float* __restrict__ out)
{
  const int e = blockIdx.z, mt = blockIdx.y, nt = blockIdx.x;
  const int n_e = meta[e];
  const int m0 = mt * BM;
  if (m0 >= n_e) return;
  const int base = meta[8 + e];
  const int tile = meta[24 + e] + mt;

  const int tid = threadIdx.x, lane = tid & 63, wid = tid >> 6;
  const int wm = wid >> 1, wn = wid & 1;
  const int kq = lane >> 4, l15 = lane & 15;

  const char* aBase = utile + (size_t)tile * NKT * TILE_BYTES + kq * 4096 + (wm * 64 + l15) * 16;
  const char* bBase[2];
  #pragma unroll
  for (int fn = 0; fn < 2; ++fn) {
    int col = nt * BN2 + wn * 32 + fn * 16 + l15;
    bBase[fn] = (const char*)dwn + (size_t)(e * HIDDEN + col) * (INTER * 4) + kq * 32;
  }

  f32x4 acc[4][2];
  #pragma unroll
  for (int fm = 0; fm < 4; ++fm)
    #pragma unroll
    for (int fn = 0; fn < 2; ++fn)
      acc[fm][fn] = f32x4{0.f, 0.f, 0.f, 0.f};

  bf16x8 a0[4], a1[4], a2[4];
  float4 b0[2][2], b1[2][2], b2[2][2];

#define LOAD2(kt, aR, bR) { \
    const char* ap = aBase + (size_t)(kt) * TILE_BYTES; \
    _Pragma("unroll") for (int fm = 0; fm < 4; ++fm) \
      aR[fm] = *(const bf16x8*)(ap + fm * 256); \
    _Pragma("unroll") for (int fn = 0; fn < 2; ++fn) { \
      bR[fn][0] = *(const float4*)(bBase[fn] + (size_t)(kt) * 128); \
      bR[fn][1] = *(const float4*)(bBase[fn] + (size_t)(kt) * 128 + 16); } }

#define COMP2(aR, bR) { bf16x8 bb[2]; \
    _Pragma("unroll") for (int fn = 0; fn < 2; ++fn) bb[fn] = cvt8(bR[fn][0], bR[fn][1]); \
    _Pragma("unroll") for (int fm = 0; fm < 4; ++fm) \
      _Pragma("unroll") for (int fn = 0; fn < 2; ++fn) \
        acc[fm][fn] = __builtin_amdgcn_mfma_f32_16x16x32_bf16(aR[fm], bb[fn], acc[fm][fn], 0, 0, 0); }

  LOAD2(0, a0, b0);
  LOAD2(1, a1, b1);
  LOAD2(2, a2, b2);
  for (int kt = 0; kt < NKT; kt += 3) {
    COMP2(a0, b0);
    if (kt + 3 < NKT) LOAD2(kt + 3, a0, b0);
    COMP2(a1, b1);
    if (kt + 4 < NKT) LOAD2(kt + 4, a1, b1);
    COMP2(a2, b2);
    if (kt + 5 < NKT) LOAD2(kt + 5, a2, b2);
  }

  #pragma unroll
  for (int fm = 0; fm < 4; ++fm) {
    #pragma unroll
    for (int j = 0; j < 4; ++j) {
      int rL = m0 + wm * 64 + fm * 16 + kq * 4 + j;
      int aidx = (rL < n_e) ? list[base + rL] : -1;
      #pragma unroll
      for (int fn = 0; fn < 2; ++fn) {
        int col = nt * BN2 + wn * 32 + fn * 16 + l15;
        if (aidx >= 0)
          out[(size_t)aidx * HIDDEN + col] = acc[fm][fn][j] + dbias[e * HIDDEN + col];
      }
    }
  }
}

extern "C" void kernel_launch(void* const* d_in, const int* in_sizes, int n_in,
                              void* d_out, int out_size, void* d_ws, size_t ws_size,
                              hipStream_t stream) {
  const float* t     = (const float*)d_in[0];
  const int*   eidx  = (const int*)d_in[1];
  const float* gup   = (const float*)d_in[2];
  const float* gub   = (const float*)d_in[3];
  const float* dwn   = (const float*)d_in[4];
  const float* dbias = (const float*)d_in[5];
  float* out = (float*)d_out;

  char* ws = (char*)d_ws;
  char* atile = ws;                        // IMG_BYTES
  char* utile = ws + IMG_BYTES;            // IMG_BYTES
  int* meta = (int*)(ws + 2 * IMG_BYTES);  // 32 ints
  int* list = meta + 32;                   // 2048 ints

  route_count<<<1, 256, 0, stream>>>(eidx, meta);
  route_scatter<<<NPAIR / 256, 256, 0, stream>>>(eidx, meta, list);
  gather_a<<<NPAIR, 256, 0, stream>>>(t, eidx, meta, list, atile);

  dim3 g1(GUP_ROWS / BN1, MT_GRID, NEXP);   // 60 x 8 x 8
  gemm1_swiglu<<<g1, 512, 0, stream>>>(atile, gup, gub, meta, utile);

  dim3 g2(HIDDEN / BN2, MT_GRID, NEXP);     // 45 x 8 x 8
  gemm2_down<<<g2, 512, 0, stream>>>(utile, dwn, dbias, meta, list, out);
}

// Round 8
// 431.731 us; speedup vs baseline: 2.2111x; 2.2111x over previous
//
#include <hip/hip_runtime.h>
#include <hip/hip_bf16.h>

#define HIDDEN   2880
#define INTER    2880
#define NEXP     8
#define GUP_ROWS 5760
#define NPAIR    2048

#define NKT  90              // k-tiles of 32
#define BM   256
#define BN   64              // both gemms: 64 cols/block
#define MT_GRID 8

#define MAXTILES 16
#define TILE_BYTES 16384     // (tile,kt): 4 kq-planes x 256 rows x 16B
#define IMG_BYTES ((size_t)MAXTILES * NKT * TILE_BYTES)

using bf16x8 = __attribute__((ext_vector_type(8))) short;
using f32x4  = __attribute__((ext_vector_type(4))) float;

typedef const __attribute__((address_space(1))) unsigned GBuf;
typedef __attribute__((address_space(3))) unsigned LBuf;

__device__ __forceinline__ void gl2lds(const void* g, void* l) {
  __builtin_amdgcn_global_load_lds((GBuf*)g, (LBuf*)l, 16, 0, 0);
}
__device__ __forceinline__ void wait_vm6() {
  asm volatile("s_waitcnt vmcnt(6)" ::: "memory");
  __builtin_amdgcn_sched_barrier(0);
}
__device__ __forceinline__ void wait_vm0() {
  asm volatile("s_waitcnt vmcnt(0)" ::: "memory");
  __builtin_amdgcn_sched_barrier(0);
}
__device__ __forceinline__ void barrier() {
  __builtin_amdgcn_sched_barrier(0);
  __builtin_amdgcn_s_barrier();
  __builtin_amdgcn_sched_barrier(0);
}

__device__ __forceinline__ unsigned cvt2bf(float a, float b) {
  union { __hip_bfloat16 h; unsigned short s; } x, y;
  x.h = __float2bfloat16(a);
  y.h = __float2bfloat16(b);
  return (unsigned)x.s | ((unsigned)y.s << 16);
}
__device__ __forceinline__ bf16x8 cvt8(const float4& lo, const float4& hi) {
  union { bf16x8 v; unsigned u[4]; } r;
  r.u[0] = cvt2bf(lo.x, lo.y);
  r.u[1] = cvt2bf(lo.z, lo.w);
  r.u[2] = cvt2bf(hi.x, hi.y);
  r.u[3] = cvt2bf(hi.z, hi.w);
  return r.v;
}

// ---------------- routing ----------------
// meta: [0..7]=counts [8..15]=row offsets [16..23]=cursor [24..31]=tile base
__global__ void route_count(const int* __restrict__ eidx, int* __restrict__ meta) {
  __shared__ int cnt[NEXP];
  int t = threadIdx.x;
  if (t < NEXP) cnt[t] = 0;
  __syncthreads();
  for (int a = t; a < NPAIR; a += 256) atomicAdd(&cnt[eidx[a]], 1);
  __syncthreads();
  if (t == 0) {
    int off = 0, toff = 0;
    for (int e = 0; e < NEXP; ++e) {
      meta[e] = cnt[e];
      meta[8 + e] = off;
      meta[16 + e] = off;
      meta[24 + e] = toff;
      off += cnt[e];
      toff += (cnt[e] + 255) >> 8;
    }
  }
}

__global__ void route_scatter(const int* __restrict__ eidx, int* __restrict__ meta,
                              int* __restrict__ list) {
  int a = blockIdx.x * 256 + threadIdx.x;
  int e = eidx[a];
  int pos = atomicAdd(&meta[16 + e], 1);
  list[pos] = a;
}

// ---------------- gather A rows -> bf16 tiled fragment image ----------------
// layout: [tile][kt][kq 0..3][row 0..255][16B]
__global__ void gather_a(const float* __restrict__ t, const int* __restrict__ eidx,
                         const int* __restrict__ meta, const int* __restrict__ list,
                         char* __restrict__ atile) {
  const int i = blockIdx.x;
  const int a = list[i];
  const int e = eidx[a];
  const int r = i - meta[8 + e];
  const int tile = meta[24 + e] + (r >> 8);
  const int row = r & 255;
  const float* src = t + (size_t)(a >> 2) * HIDDEN;
  for (int ch = threadIdx.x; ch < HIDDEN / 8; ch += 256) {
    int kt = ch >> 2, kq = ch & 3;
    const float4* s = (const float4*)(src + ch * 8);
    float4 v0 = s[0], v1 = s[1];
    uint4 w;
    w.x = cvt2bf(v0.x, v0.y); w.y = cvt2bf(v0.z, v0.w);
    w.z = cvt2bf(v1.x, v1.y); w.w = cvt2bf(v1.z, v1.w);
    *(uint4*)(atile + (size_t)(tile * NKT + kt) * TILE_BYTES + kq * 4096 + row * 16) = w;
  }
}

// ---------------- shared GEMM core: 4 waves, tile 256x64, wave tile 64x64 ----------------
// LDS: A 2x16KB + B 2x8KB = 48KB -> 3 blocks/CU.
// Staging: 24 chunks of 1KB (16 A-image + 8 B-f32-colmajor), 6 glds/wave.

// grid: (e, nt, mt)  -> expert cycles fastest in flat id => XCD affinity
template<int NCOLS_TOT, bool SWIGLU>
__global__ __launch_bounds__(256, 3)
void gemm_core(const char* __restrict__ aimg,
               const float* __restrict__ wgt,
               const float* __restrict__ wbias,
               const int* __restrict__ meta,
               const int* __restrict__ list,
               char* __restrict__ uimg,
               float* __restrict__ out)
{
  const int e = blockIdx.x, nt = blockIdx.y, mt = blockIdx.z;
  const int n_e = meta[e];
  const int m0 = mt * BM;
  if (m0 >= n_e) return;
  const int tile = meta[24 + e] + mt;

  __shared__ __align__(16) char lds[49152];

  const int tid = threadIdx.x, lane = tid & 63, wid = tid >> 6;
  const int wm = wid;                 // 4 wm groups x 64 rows
  const int kq = lane >> 4, l15 = lane & 15, l7 = lane & 7;

  const size_t tileBase = (size_t)tile * NKT * TILE_BYTES;

  // 6 chunks per wave: chunk c = wid*6 + j;  c<16 -> A, else B (cb = c-16, 8 cols)
  const char* srcP[6]; int dstOff[6]; int strd[6]; int bufStr[6];
  #pragma unroll
  for (int j = 0; j < 6; ++j) {
    int c = wid * 6 + j;
    if (c < 16) {
      srcP[j] = aimg + tileBase + c * 1024 + lane * 16;
      strd[j] = TILE_BYTES;
      dstOff[j] = c * 1024;
      bufStr[j] = 16384;
    } else {
      int cb = c - 16;
      int colt = cb * 8 + (lane >> 3);
      int segg = l7 ^ (colt & 7);
      srcP[j] = (const char*)wgt +
                ((size_t)(e * NCOLS_TOT + nt * BN + colt) * HIDDEN) * 4 + segg * 16;
      strd[j] = 128;
      dstOff[j] = 32768 + cb * 1024;
      bufStr[j] = 8192;
    }
  }

  auto STAGE = [&](int kt, int buf) {
    #pragma unroll
    for (int j = 0; j < 6; ++j)
      gl2lds(srcP[j] + (size_t)kt * strd[j], lds + dstOff[j] + buf * bufStr[j]);
  };

  f32x4 acc[4][4];
  #pragma unroll
  for (int fm = 0; fm < 4; ++fm)
    #pragma unroll
    for (int fn = 0; fn < 4; ++fn)
      acc[fm][fn] = f32x4{0.f, 0.f, 0.f, 0.f};

  auto COMP = [&](int buf) {
    const char* aB = lds + buf * 16384 + kq * 4096;
    const char* bB = lds + 32768 + buf * 8192;
    const int arow = wm * 64 + l15;
    bf16x8 af[4], bf[4];
    #pragma unroll
    for (int fm = 0; fm < 4; ++fm)
      af[fm] = *(const bf16x8*)(aB + (arow + fm * 16) * 16);
    #pragma unroll
    for (int fn = 0; fn < 4; ++fn) {
      const int col = fn * 16 + l15;
      const char* cbp = bB + col * 128;
      float4 lo = *(const float4*)(cbp + (((kq * 2) ^ l7) << 4));
      float4 hi = *(const float4*)(cbp + (((kq * 2 + 1) ^ l7) << 4));
      bf[fn] = cvt8(lo, hi);
    }
    #pragma unroll
    for (int fm = 0; fm < 4; ++fm)
      #pragma unroll
      for (int fn = 0; fn < 4; ++fn)
        acc[fm][fn] = __builtin_amdgcn_mfma_f32_16x16x32_bf16(af[fm], bf[fn], acc[fm][fn], 0, 0, 0);
  };

  STAGE(0, 0);
  for (int kt = 0; kt < NKT; ++kt) {
    if (kt + 1 < NKT) { STAGE(kt + 1, (kt + 1) & 1); wait_vm6(); }
    else wait_vm0();
    barrier();
    COMP(kt & 1);
    barrier();
  }

  if (SWIGLU) {
    // +bias, swiglu (even col = glu, odd = lin), write u into uimg
    #pragma unroll
    for (int fm = 0; fm < 4; ++fm) {
      #pragma unroll
      for (int fn = 0; fn < 4; ++fn) {
        const int colg = nt * BN + fn * 16 + l15;
        const float bias = wbias[e * NCOLS_TOT + colg];
        #pragma unroll
        for (int j = 0; j < 4; ++j) {
          float h = acc[fm][fn][j] + bias;
          float other = __shfl_xor(h, 1, 64);
          int rowin = wm * 64 + fm * 16 + kq * 4 + j;
          if (!(lane & 1) && (m0 + rowin) < n_e) {
            float xg = fminf(h, 7.0f);
            float xl = fminf(fmaxf(other, -7.0f), 7.0f);
            float og = xg / (1.0f + __expf(-1.702f * xg));
            float uv = og * (xl + 1.0f);
            int uc = colg >> 1;
            int kt2 = uc >> 5, kq2 = (uc >> 3) & 3;
            *(__hip_bfloat16*)(uimg + (size_t)(tile * NKT + kt2) * TILE_BYTES +
                kq2 * 4096 + rowin * 16 + (uc & 7) * 2) = __float2bfloat16(uv);
          }
        }
      }
    }
  } else {
    const int base = meta[8 + e];
    #pragma unroll
    for (int fm = 0; fm < 4; ++fm) {
      #pragma unroll
      for (int j = 0; j < 4; ++j) {
        int rL = m0 + wm * 64 + fm * 16 + kq * 4 + j;
        int aidx = (rL < n_e) ? list[base + rL] : -1;
        #pragma unroll
        for (int fn = 0; fn < 4; ++fn) {
          int col = nt * BN + fn * 16 + l15;
          if (aidx >= 0)
            out[(size_t)aidx * HIDDEN + col] = acc[fm][fn][j] + wbias[e * NCOLS_TOT + col];
        }
      }
    }
  }
}

extern "C" void kernel_launch(void* const* d_in, const int* in_sizes, int n_in,
                              void* d_out, int out_size, void* d_ws, size_t ws_size,
                              hipStream_t stream) {
  const float* t     = (const float*)d_in[0];
  const int*   eidx  = (const int*)d_in[1];
  const float* gup   = (const float*)d_in[2];
  const float* gub   = (const float*)d_in[3];
  const float* dwn   = (const float*)d_in[4];
  const float* dbias = (const float*)d_in[5];
  float* out = (float*)d_out;

  char* ws = (char*)d_ws;
  char* atile = ws;
  char* utile = ws + IMG_BYTES;
  int* meta = (int*)(ws + 2 * IMG_BYTES);
  int* list = meta + 32;

  route_count<<<1, 256, 0, stream>>>(eidx, meta);
  route_scatter<<<NPAIR / 256, 256, 0, stream>>>(eidx, meta, list);
  gather_a<<<NPAIR, 256, 0, stream>>>(t, eidx, meta, list, atile);

  dim3 g1(NEXP, GUP_ROWS / BN, MT_GRID);   // 8 x 90 x 8
  gemm_core<GUP_ROWS, true><<<g1, 256, 0, stream>>>(atile, gup, gub, meta, list, utile, out);

  dim3 g2(NEXP, HIDDEN / BN, MT_GRID);     // 8 x 45 x 8
  gemm_core<HIDDEN, false><<<g2, 256, 0, stream>>>(utile, dwn, dbias, meta, list, nullptr, out);
}